// Round 1
// baseline (487.453 us; speedup 1.0000x reference)
//
#include <hip/hip_runtime.h>

#define DIN 256
#define DH  64
#define DOUT 4

// ---------------------------------------------------------------------------
// deg[i] = number of edges with dst == i
__global__ void deg_kernel(const int* __restrict__ dst, float* __restrict__ deg, int E) {
    int e = blockIdx.x * blockDim.x + threadIdx.x;
    if (e < E) atomicAdd(&deg[dst[e]], 1.0f);
}

// ---------------------------------------------------------------------------
// GEMM1: y[N,128] = x[N,256] @ [W1_l | W1_r]   (each W is [256,64] row-major)
// Tile 64 rows x 128 cols, BK=32, 256 threads, per-thread 8x4 register tile.
__global__ __launch_bounds__(256) void gemm1_kernel(
    const float* __restrict__ x, const float* __restrict__ Wl,
    const float* __restrict__ Wr, float* __restrict__ y, int N)
{
    __shared__ float xs[64][36];     // +4 pad keeps float4 alignment
    __shared__ float ws[32][128];

    const int tid = threadIdx.x;
    const int block_row = blockIdx.x * 64;
    const int c0 = (tid & 31) * 4;   // col group: 4 cols, lanes 0..31 cover 128 cols
    const int r0 = (tid >> 5) * 8;   // row group: 8 rows

    float acc[8][4] = {};

    for (int kc = 0; kc < DIN; kc += 32) {
        // ---- stage x tile: 64 rows x 32 k's
        {
            const int lr = tid >> 3;          // 0..31
            const int lc = (tid & 7) * 4;     // 0,4,...,28
            #pragma unroll
            for (int p = 0; p < 2; ++p) {
                const int row  = lr + p * 32;
                const int grow = block_row + row;
                float4 v = make_float4(0.f, 0.f, 0.f, 0.f);
                if (grow < N)
                    v = *(const float4*)(x + (size_t)grow * DIN + kc + lc);
                *(float4*)(&xs[row][lc]) = v;
            }
        }
        // ---- stage W tile: 32 k's x 128 cols (64 from Wl, 64 from Wr)
        {
            const int kr = tid >> 5;          // 0..7
            const int wc = (tid & 31) * 4;    // 0..124
            #pragma unroll
            for (int p = 0; p < 4; ++p) {
                const int krow = kc + kr + p * 8;
                float4 v;
                if (wc < 64) v = *(const float4*)(Wl + krow * 64 + wc);
                else         v = *(const float4*)(Wr + krow * 64 + (wc - 64));
                *(float4*)(&ws[kr + p * 8][wc]) = v;
            }
        }
        __syncthreads();

        #pragma unroll
        for (int kk = 0; kk < 32; kk += 4) {
            float4 wv[4];
            #pragma unroll
            for (int j = 0; j < 4; ++j)
                wv[j] = *(const float4*)(&ws[kk + j][c0]);
            #pragma unroll
            for (int i = 0; i < 8; ++i) {
                const float4 xv = *(const float4*)(&xs[r0 + i][kk]);
                acc[i][0] += xv.x * wv[0].x + xv.y * wv[1].x + xv.z * wv[2].x + xv.w * wv[3].x;
                acc[i][1] += xv.x * wv[0].y + xv.y * wv[1].y + xv.z * wv[2].y + xv.w * wv[3].y;
                acc[i][2] += xv.x * wv[0].z + xv.y * wv[1].z + xv.z * wv[2].z + xv.w * wv[3].z;
                acc[i][3] += xv.x * wv[0].w + xv.y * wv[1].w + xv.z * wv[2].w + xv.w * wv[3].w;
            }
        }
        __syncthreads();
    }

    #pragma unroll
    for (int i = 0; i < 8; ++i) {
        const int grow = block_row + r0 + i;
        if (grow < N)
            *(float4*)(y + (size_t)grow * 128 + c0) =
                make_float4(acc[i][0], acc[i][1], acc[i][2], acc[i][3]);
    }
}

// ---------------------------------------------------------------------------
// scatter1: agg1[dst, f] += y_l[src, f]   (f in 0..63; y_l = y[:,0:64])
__global__ void scatter1_kernel(const int* __restrict__ src, const int* __restrict__ dst,
                                const float* __restrict__ y, float* __restrict__ agg,
                                int E)
{
    const int idx = blockIdx.x * blockDim.x + threadIdx.x;
    if (idx >= E * 64) return;
    const int e = idx >> 6;
    const int f = idx & 63;
    const int s = src[e];
    const int d = dst[e];
    atomicAdd(&agg[(size_t)d * 64 + f], y[(size_t)s * 128 + f]);
}

// ---------------------------------------------------------------------------
// node1: h = relu( normalize( agg1/deg + b1_l + y_r ) )
__global__ void node1_kernel(const float* __restrict__ agg, const float* __restrict__ y,
                             const float* __restrict__ deg, const float* __restrict__ b,
                             float* __restrict__ h, int N)
{
    const int i = blockIdx.x * blockDim.x + threadIdx.x;
    if (i >= N) return;
    const float dinv = 1.0f / fmaxf(deg[i], 1.0f);

    float v[64];
    float ss = 0.f;
    const float4* ag = (const float4*)(agg + (size_t)i * 64);
    const float4* yr = (const float4*)(y + (size_t)i * 128 + 64);
    #pragma unroll
    for (int q = 0; q < 16; ++q) {
        const float4 a  = ag[q];
        const float4 r  = yr[q];
        const float4 bb = *(const float4*)(b + q * 4);
        float4 o;
        o.x = a.x * dinv + bb.x + r.x;
        o.y = a.y * dinv + bb.y + r.y;
        o.z = a.z * dinv + bb.z + r.z;
        o.w = a.w * dinv + bb.w + r.w;
        ss += o.x * o.x + o.y * o.y + o.z * o.z + o.w * o.w;
        v[q * 4 + 0] = o.x; v[q * 4 + 1] = o.y; v[q * 4 + 2] = o.z; v[q * 4 + 3] = o.w;
    }
    const float inv = 1.0f / fmaxf(sqrtf(ss), 1e-12f);
    float4* hr = (float4*)(h + (size_t)i * 64);
    #pragma unroll
    for (int q = 0; q < 16; ++q) {
        float4 o;
        o.x = fmaxf(v[q * 4 + 0] * inv, 0.f);
        o.y = fmaxf(v[q * 4 + 1] * inv, 0.f);
        o.z = fmaxf(v[q * 4 + 2] * inv, 0.f);
        o.w = fmaxf(v[q * 4 + 3] * inv, 0.f);
        hr[q] = o;
    }
}

// ---------------------------------------------------------------------------
// GEMM2: z[N,8] = h[N,64] @ [W2_l | W2_r]  (each [64,4] row-major)
__global__ __launch_bounds__(256) void gemm2_kernel(
    const float* __restrict__ h, const float* __restrict__ Wl,
    const float* __restrict__ Wr, float* __restrict__ z, int N)
{
    __shared__ float wls[64][4];
    __shared__ float wrs[64][4];
    const int tid = threadIdx.x;
    wls[tid >> 2][tid & 3] = Wl[tid];
    wrs[tid >> 2][tid & 3] = Wr[tid];
    __syncthreads();

    const int i = blockIdx.x * blockDim.x + tid;
    if (i >= N) return;

    float accl[4] = {}, accr[4] = {};
    const float4* hr = (const float4*)(h + (size_t)i * 64);
    #pragma unroll
    for (int q = 0; q < 16; ++q) {
        const float4 hv = hr[q];
        const int k = q * 4;
        #pragma unroll
        for (int c = 0; c < 4; ++c) {
            accl[c] += hv.x * wls[k][c] + hv.y * wls[k + 1][c]
                     + hv.z * wls[k + 2][c] + hv.w * wls[k + 3][c];
            accr[c] += hv.x * wrs[k][c] + hv.y * wrs[k + 1][c]
                     + hv.z * wrs[k + 2][c] + hv.w * wrs[k + 3][c];
        }
    }
    float* zp = z + (size_t)i * 8;
    *(float4*)(zp)     = make_float4(accl[0], accl[1], accl[2], accl[3]);
    *(float4*)(zp + 4) = make_float4(accr[0], accr[1], accr[2], accr[3]);
}

// ---------------------------------------------------------------------------
// scatter2: agg2[dst, f] += z_l[src, f]   (f in 0..3)
__global__ void scatter2_kernel(const int* __restrict__ src, const int* __restrict__ dst,
                                const float* __restrict__ z, float* __restrict__ agg,
                                int E)
{
    const int idx = blockIdx.x * blockDim.x + threadIdx.x;
    if (idx >= E * 4) return;
    const int e = idx >> 2;
    const int f = idx & 3;
    const int s = src[e];
    const int d = dst[e];
    atomicAdd(&agg[(size_t)d * 4 + f], z[(size_t)s * 8 + f]);
}

// ---------------------------------------------------------------------------
// node2: out = normalize( agg2/deg + b2_l + z_r )
__global__ void node2_kernel(const float* __restrict__ agg, const float* __restrict__ z,
                             const float* __restrict__ deg, const float* __restrict__ b,
                             float* __restrict__ out, int N)
{
    const int i = blockIdx.x * blockDim.x + threadIdx.x;
    if (i >= N) return;
    const float dinv = 1.0f / fmaxf(deg[i], 1.0f);
    const float4 a  = *(const float4*)(agg + (size_t)i * 4);
    const float4 r  = *(const float4*)(z + (size_t)i * 8 + 4);
    const float4 bb = *(const float4*)(b);
    float4 o;
    o.x = a.x * dinv + bb.x + r.x;
    o.y = a.y * dinv + bb.y + r.y;
    o.z = a.z * dinv + bb.z + r.z;
    o.w = a.w * dinv + bb.w + r.w;
    const float ss = o.x * o.x + o.y * o.y + o.z * o.z + o.w * o.w;
    const float inv = 1.0f / fmaxf(sqrtf(ss), 1e-12f);
    o.x *= inv; o.y *= inv; o.z *= inv; o.w *= inv;
    *(float4*)(out + (size_t)i * 4) = o;
}

// ---------------------------------------------------------------------------
extern "C" void kernel_launch(void* const* d_in, const int* in_sizes, int n_in,
                              void* d_out, int out_size, void* d_ws, size_t ws_size,
                              hipStream_t stream)
{
    const float* x    = (const float*)d_in[0];
    const int*   ei   = (const int*)d_in[1];
    const float* W1l  = (const float*)d_in[2];
    const float* b1l  = (const float*)d_in[3];
    const float* W1r  = (const float*)d_in[4];
    const float* W2l  = (const float*)d_in[5];
    const float* b2l  = (const float*)d_in[6];
    const float* W2r  = (const float*)d_in[7];
    float* out = (float*)d_out;

    const int N = in_sizes[0] / DIN;
    const int E = in_sizes[1] / 2;
    const int* src = ei;
    const int* dst = ei + E;

    // workspace layout
    char* ws = (char*)d_ws;
    size_t off = 0;
    auto alloc = [&](size_t bytes) {
        void* p = ws + off;
        off += (bytes + 255) & ~(size_t)255;
        return p;
    };
    float* deg  = (float*)alloc((size_t)N * 4);
    float* y    = (float*)alloc((size_t)N * 128 * 4);
    float* agg1 = (float*)alloc((size_t)N * 64 * 4);
    float* h    = (float*)alloc((size_t)N * 64 * 4);
    float* z    = (float*)alloc((size_t)N * 8 * 4);
    float* agg2 = (float*)alloc((size_t)N * 4 * 4);

    // zero accumulators
    hipMemsetAsync(deg,  0, (size_t)N * 4, stream);
    hipMemsetAsync(agg1, 0, (size_t)N * 64 * 4, stream);
    hipMemsetAsync(agg2, 0, (size_t)N * 4 * 4, stream);

    deg_kernel<<<(E + 255) / 256, 256, 0, stream>>>(dst, deg, E);

    gemm1_kernel<<<(N + 63) / 64, 256, 0, stream>>>(x, W1l, W1r, y, N);

    {
        const long long tot = (long long)E * 64;
        scatter1_kernel<<<(int)((tot + 255) / 256), 256, 0, stream>>>(src, dst, y, agg1, E);
    }

    node1_kernel<<<(N + 255) / 256, 256, 0, stream>>>(agg1, y, deg, b1l, h, N);

    gemm2_kernel<<<(N + 255) / 256, 256, 0, stream>>>(h, W2l, W2r, z, N);

    {
        const long long tot = (long long)E * 4;
        scatter2_kernel<<<(int)((tot + 255) / 256), 256, 0, stream>>>(src, dst, z, agg2, E);
    }

    node2_kernel<<<(N + 255) / 256, 256, 0, stream>>>(agg2, z, deg, b2l, out, N);
}

// Round 3
// 340.968 us; speedup vs baseline: 1.4296x; 1.4296x over previous
//
#include <hip/hip_runtime.h>

#define DIN 256
#define DH  64
#define DOUT 4

typedef __attribute__((ext_vector_type(8))) short bf16x8;
typedef __attribute__((ext_vector_type(4))) float f32x4;

__device__ __forceinline__ short f2bf(float f) {
    unsigned int u = __float_as_uint(f);
    unsigned int r = (u + 0x7FFFu + ((u >> 16) & 1u)) >> 16;
    return (short)r;
}
__device__ __forceinline__ float bf2f(short h) {
    return __uint_as_float(((unsigned int)(unsigned short)h) << 16);
}

// ---------------------------------------------------------------------------
// deg[i] = number of edges with dst == i
__global__ void deg_kernel(const int* __restrict__ dst, float* __restrict__ deg, int E) {
    int e = blockIdx.x * blockDim.x + threadIdx.x;
    if (e < E) atomicAdd(&deg[dst[e]], 1.0f);
}

// ---------------------------------------------------------------------------
// W prep: split [W1_l | W1_r]^T into hi/lo bf16: WT[n][k], n=0..127, k=0..255
__global__ void wprep_kernel(const float* __restrict__ Wl, const float* __restrict__ Wr,
                             short* __restrict__ WTh, short* __restrict__ WTl) {
    const int k = threadIdx.x;   // 0..255
    const int n = blockIdx.x;    // 0..127
    const float v = (n < 64) ? Wl[k * 64 + n] : Wr[k * 64 + (n - 64)];
    const short hi = f2bf(v);
    const short lo = f2bf(v - bf2f(hi));
    WTh[n * 256 + k] = hi;
    WTl[n * 256 + k] = lo;
}

// ---------------------------------------------------------------------------
// GEMM1 (split-bf16 MFMA): y[N,128] = x[N,256] @ [W1_l | W1_r], fp32-accurate.
// acc += x_hi@W_hi + x_hi@W_lo + x_lo@W_hi  (lo*lo dropped, ~2^-18 relative)
// Block: 64 rows x 128 cols, BK=32, 256 threads (4 waves).
// Wave w owns cols [w*32, w*32+32): 4 M-tiles x 2 N-tiles of 16x16x32 MFMA.
#define XS_LD 40   // 32 + 8 pad (bf16 elems); row stride 80 B, 16B aligned
__global__ __launch_bounds__(256) void gemm1_mfma(
    const float* __restrict__ x, const short* __restrict__ WTh,
    const short* __restrict__ WTl, float* __restrict__ y, int N)
{
    __shared__ short xsh[64 * XS_LD];    // 5120 B
    __shared__ short xsl[64 * XS_LD];
    __shared__ short wth[128 * XS_LD];   // 10240 B
    __shared__ short wtl[128 * XS_LD];

    const int tid  = threadIdx.x;
    const int wave = tid >> 6;
    const int lane = tid & 63;
    const int lm   = lane & 15;
    const int quad = lane >> 4;
    const int brow = blockIdx.x * 64;

    f32x4 acc[4][2];
    #pragma unroll
    for (int mt = 0; mt < 4; ++mt)
        #pragma unroll
        for (int nt = 0; nt < 2; ++nt)
            acc[mt][nt] = (f32x4){0.f, 0.f, 0.f, 0.f};

    // staging index precompute
    const int xr  = tid >> 2;            // 0..63  (x row within tile)
    const int xkp = (tid & 3) * 8;       // k sub-offset 0/8/16/24
    const int wn  = tid >> 1;            // 0..127 (WT row = output col)
    const int wkp = (tid & 1) * 16;      // k sub-offset 0/16

    for (int kc = 0; kc < DIN; kc += 32) {
        // ---- stage x tile (64 rows x 32 k), fp32 -> hi/lo bf16
        {
            const int row_g = brow + xr;
            float4 f0, f1;
            if (row_g < N) {
                const float4* xp = (const float4*)(x + (size_t)row_g * DIN + kc + xkp);
                f0 = xp[0]; f1 = xp[1];
            } else {
                f0 = f1 = make_float4(0.f, 0.f, 0.f, 0.f);
            }
            bf16x8 ph, pl;
            float fv[8] = {f0.x, f0.y, f0.z, f0.w, f1.x, f1.y, f1.z, f1.w};
            #pragma unroll
            for (int j = 0; j < 8; ++j) {
                const short hi = f2bf(fv[j]);
                ph[j] = hi;
                pl[j] = f2bf(fv[j] - bf2f(hi));
            }
            *(bf16x8*)(&xsh[xr * XS_LD + xkp]) = ph;
            *(bf16x8*)(&xsl[xr * XS_LD + xkp]) = pl;
        }
        // ---- stage W tile (128 cols x 32 k) from preconverted hi/lo bf16
        {
            const size_t gw = (size_t)wn * 256 + kc + wkp;
            const bf16x8* wph = (const bf16x8*)(WTh + gw);
            const bf16x8* wpl = (const bf16x8*)(WTl + gw);
            *(bf16x8*)(&wth[wn * XS_LD + wkp])     = wph[0];
            *(bf16x8*)(&wth[wn * XS_LD + wkp + 8]) = wph[1];
            *(bf16x8*)(&wtl[wn * XS_LD + wkp])     = wpl[0];
            *(bf16x8*)(&wtl[wn * XS_LD + wkp + 8]) = wpl[1];
        }
        __syncthreads();

        bf16x8 ah[4], al[4], bh[2], bl[2];
        #pragma unroll
        for (int mt = 0; mt < 4; ++mt) {
            const int off = (mt * 16 + lm) * XS_LD + quad * 8;
            ah[mt] = *(const bf16x8*)(&xsh[off]);
            al[mt] = *(const bf16x8*)(&xsl[off]);
        }
        #pragma unroll
        for (int nt = 0; nt < 2; ++nt) {
            const int off = (wave * 32 + nt * 16 + lm) * XS_LD + quad * 8;
            bh[nt] = *(const bf16x8*)(&wth[off]);
            bl[nt] = *(const bf16x8*)(&wtl[off]);
        }
        #pragma unroll
        for (int mt = 0; mt < 4; ++mt)
            #pragma unroll
            for (int nt = 0; nt < 2; ++nt) {
                acc[mt][nt] = __builtin_amdgcn_mfma_f32_16x16x32_bf16(
                    ah[mt], bh[nt], acc[mt][nt], 0, 0, 0);
                acc[mt][nt] = __builtin_amdgcn_mfma_f32_16x16x32_bf16(
                    ah[mt], bl[nt], acc[mt][nt], 0, 0, 0);
                acc[mt][nt] = __builtin_amdgcn_mfma_f32_16x16x32_bf16(
                    al[mt], bh[nt], acc[mt][nt], 0, 0, 0);
            }
        __syncthreads();
    }

    // ---- epilogue: C/D layout col=lane&15, row=quad*4+reg
    #pragma unroll
    for (int mt = 0; mt < 4; ++mt) {
        #pragma unroll
        for (int r = 0; r < 4; ++r) {
            const int row_g = brow + mt * 16 + quad * 4 + r;
            if (row_g < N) {
                const int col = wave * 32 + lm;
                float* yp = y + (size_t)row_g * 128 + col;
                yp[0]  = acc[mt][0][r];
                yp[16] = acc[mt][1][r];
            }
        }
    }
}

// ---------------------------------------------------------------------------
// scatter1: agg1[dst, f] += y_l[src, f]   (f in 0..63; y_l = y[:,0:64])
__global__ void scatter1_kernel(const int* __restrict__ src, const int* __restrict__ dst,
                                const float* __restrict__ y, float* __restrict__ agg,
                                int E)
{
    const int idx = blockIdx.x * blockDim.x + threadIdx.x;
    if (idx >= E * 64) return;
    const int e = idx >> 6;
    const int f = idx & 63;
    const int s = src[e];
    const int d = dst[e];
    atomicAdd(&agg[(size_t)d * 64 + f], y[(size_t)s * 128 + f]);
}

// ---------------------------------------------------------------------------
// node1: h = relu( normalize( agg1/deg + b1_l + y_r ) )
__global__ void node1_kernel(const float* __restrict__ agg, const float* __restrict__ y,
                             const float* __restrict__ deg, const float* __restrict__ b,
                             float* __restrict__ h, int N)
{
    const int i = blockIdx.x * blockDim.x + threadIdx.x;
    if (i >= N) return;
    const float dinv = 1.0f / fmaxf(deg[i], 1.0f);

    float v[64];
    float ss = 0.f;
    const float4* ag = (const float4*)(agg + (size_t)i * 64);
    const float4* yr = (const float4*)(y + (size_t)i * 128 + 64);
    #pragma unroll
    for (int q = 0; q < 16; ++q) {
        const float4 a  = ag[q];
        const float4 r  = yr[q];
        const float4 bb = *(const float4*)(b + q * 4);
        float4 o;
        o.x = a.x * dinv + bb.x + r.x;
        o.y = a.y * dinv + bb.y + r.y;
        o.z = a.z * dinv + bb.z + r.z;
        o.w = a.w * dinv + bb.w + r.w;
        ss += o.x * o.x + o.y * o.y + o.z * o.z + o.w * o.w;
        v[q * 4 + 0] = o.x; v[q * 4 + 1] = o.y; v[q * 4 + 2] = o.z; v[q * 4 + 3] = o.w;
    }
    const float inv = 1.0f / fmaxf(sqrtf(ss), 1e-12f);
    float4* hr = (float4*)(h + (size_t)i * 64);
    #pragma unroll
    for (int q = 0; q < 16; ++q) {
        float4 o;
        o.x = fmaxf(v[q * 4 + 0] * inv, 0.f);
        o.y = fmaxf(v[q * 4 + 1] * inv, 0.f);
        o.z = fmaxf(v[q * 4 + 2] * inv, 0.f);
        o.w = fmaxf(v[q * 4 + 3] * inv, 0.f);
        hr[q] = o;
    }
}

// ---------------------------------------------------------------------------
// GEMM2: z[N,8] = h[N,64] @ [W2_l | W2_r]  (each [64,4] row-major)
__global__ __launch_bounds__(256) void gemm2_kernel(
    const float* __restrict__ h, const float* __restrict__ Wl,
    const float* __restrict__ Wr, float* __restrict__ z, int N)
{
    __shared__ float wls[64][4];
    __shared__ float wrs[64][4];
    const int tid = threadIdx.x;
    wls[tid >> 2][tid & 3] = Wl[tid];
    wrs[tid >> 2][tid & 3] = Wr[tid];
    __syncthreads();

    const int i = blockIdx.x * blockDim.x + tid;
    if (i >= N) return;

    float accl[4] = {}, accr[4] = {};
    const float4* hr = (const float4*)(h + (size_t)i * 64);
    #pragma unroll
    for (int q = 0; q < 16; ++q) {
        const float4 hv = hr[q];
        const int k = q * 4;
        #pragma unroll
        for (int c = 0; c < 4; ++c) {
            accl[c] += hv.x * wls[k][c] + hv.y * wls[k + 1][c]
                     + hv.z * wls[k + 2][c] + hv.w * wls[k + 3][c];
            accr[c] += hv.x * wrs[k][c] + hv.y * wrs[k + 1][c]
                     + hv.z * wrs[k + 2][c] + hv.w * wrs[k + 3][c];
        }
    }
    float* zp = z + (size_t)i * 8;
    *(float4*)(zp)     = make_float4(accl[0], accl[1], accl[2], accl[3]);
    *(float4*)(zp + 4) = make_float4(accr[0], accr[1], accr[2], accr[3]);
}

// ---------------------------------------------------------------------------
// scatter2: agg2[dst, f] += z_l[src, f]   (f in 0..3)
__global__ void scatter2_kernel(const int* __restrict__ src, const int* __restrict__ dst,
                                const float* __restrict__ z, float* __restrict__ agg,
                                int E)
{
    const int idx = blockIdx.x * blockDim.x + threadIdx.x;
    if (idx >= E * 4) return;
    const int e = idx >> 2;
    const int f = idx & 3;
    const int s = src[e];
    const int d = dst[e];
    atomicAdd(&agg[(size_t)d * 4 + f], z[(size_t)s * 8 + f]);
}

// ---------------------------------------------------------------------------
// node2: out = normalize( agg2/deg + b2_l + z_r )
__global__ void node2_kernel(const float* __restrict__ agg, const float* __restrict__ z,
                             const float* __restrict__ deg, const float* __restrict__ b,
                             float* __restrict__ out, int N)
{
    const int i = blockIdx.x * blockDim.x + threadIdx.x;
    if (i >= N) return;
    const float dinv = 1.0f / fmaxf(deg[i], 1.0f);
    const float4 a  = *(const float4*)(agg + (size_t)i * 4);
    const float4 r  = *(const float4*)(z + (size_t)i * 8 + 4);
    const float4 bb = *(const float4*)(b);
    float4 o;
    o.x = a.x * dinv + bb.x + r.x;
    o.y = a.y * dinv + bb.y + r.y;
    o.z = a.z * dinv + bb.z + r.z;
    o.w = a.w * dinv + bb.w + r.w;
    const float ss = o.x * o.x + o.y * o.y + o.z * o.z + o.w * o.w;
    const float inv = 1.0f / fmaxf(sqrtf(ss), 1e-12f);
    o.x *= inv; o.y *= inv; o.z *= inv; o.w *= inv;
    *(float4*)(out + (size_t)i * 4) = o;
}

// ---------------------------------------------------------------------------
extern "C" void kernel_launch(void* const* d_in, const int* in_sizes, int n_in,
                              void* d_out, int out_size, void* d_ws, size_t ws_size,
                              hipStream_t stream)
{
    const float* x    = (const float*)d_in[0];
    const int*   ei   = (const int*)d_in[1];
    const float* W1l  = (const float*)d_in[2];
    const float* b1l  = (const float*)d_in[3];
    const float* W1r  = (const float*)d_in[4];
    const float* W2l  = (const float*)d_in[5];
    const float* b2l  = (const float*)d_in[6];
    const float* W2r  = (const float*)d_in[7];
    float* out = (float*)d_out;

    const int N = in_sizes[0] / DIN;
    const int E = in_sizes[1] / 2;
    const int* src = ei;
    const int* dst = ei + E;

    // workspace layout
    char* ws = (char*)d_ws;
    size_t off = 0;
    auto alloc = [&](size_t bytes) {
        void* p = ws + off;
        off += (bytes + 255) & ~(size_t)255;
        return p;
    };
    float* deg  = (float*)alloc((size_t)N * 4);
    float* y    = (float*)alloc((size_t)N * 128 * 4);
    float* agg1 = (float*)alloc((size_t)N * 64 * 4);
    float* h    = (float*)alloc((size_t)N * 64 * 4);
    float* z    = (float*)alloc((size_t)N * 8 * 4);
    float* agg2 = (float*)alloc((size_t)N * 4 * 4);
    short* WTh  = (short*)alloc((size_t)128 * 256 * 2);
    short* WTl  = (short*)alloc((size_t)128 * 256 * 2);

    // zero accumulators
    hipMemsetAsync(deg,  0, (size_t)N * 4, stream);
    hipMemsetAsync(agg1, 0, (size_t)N * 64 * 4, stream);
    hipMemsetAsync(agg2, 0, (size_t)N * 4 * 4, stream);

    deg_kernel<<<(E + 255) / 256, 256, 0, stream>>>(dst, deg, E);

    wprep_kernel<<<128, 256, 0, stream>>>(W1l, W1r, WTh, WTl);

    gemm1_mfma<<<(N + 63) / 64, 256, 0, stream>>>(x, WTh, WTl, y, N);

    {
        const long long tot = (long long)E * 64;
        scatter1_kernel<<<(int)((tot + 255) / 256), 256, 0, stream>>>(src, dst, y, agg1, E);
    }

    node1_kernel<<<(N + 255) / 256, 256, 0, stream>>>(agg1, y, deg, b1l, h, N);

    gemm2_kernel<<<(N + 255) / 256, 256, 0, stream>>>(h, W2l, W2r, z, N);

    {
        const long long tot = (long long)E * 4;
        scatter2_kernel<<<(int)((tot + 255) / 256), 256, 0, stream>>>(src, dst, z, agg2, E);
    }

    node2_kernel<<<(N + 255) / 256, 256, 0, stream>>>(agg2, z, deg, b2l, out, N);
}

// Round 4
// 297.517 us; speedup vs baseline: 1.6384x; 1.1460x over previous
//
#include <hip/hip_runtime.h>

#define DIN 256
#define DH  64
#define DOUT 4

typedef __attribute__((ext_vector_type(8))) short bf16x8;
typedef __attribute__((ext_vector_type(4))) float f32x4;

__device__ __forceinline__ short f2bf(float f) {
    unsigned int u = __float_as_uint(f);
    unsigned int r = (u + 0x7FFFu + ((u >> 16) & 1u)) >> 16;
    return (short)r;
}
__device__ __forceinline__ float bf2f(short h) {
    return __uint_as_float(((unsigned int)(unsigned short)h) << 16);
}

// ===========================================================================
// CSR build: count -> 2-level exclusive scan -> fill
// ===========================================================================
__global__ void count_kernel(const int* __restrict__ dst, int* __restrict__ cnt, int E) {
    int e = blockIdx.x * blockDim.x + threadIdx.x;
    if (e < E) atomicAdd(&cnt[dst[e]], 1);
}

// per-block totals of cnt (256 per block)
__global__ void scan_a_kernel(const int* __restrict__ cnt, int* __restrict__ blocksum, int N) {
    __shared__ int s[256];
    const int t = threadIdx.x;
    const int gi = blockIdx.x * 256 + t;
    s[t] = (gi < N) ? cnt[gi] : 0;
    __syncthreads();
    for (int stp = 128; stp > 0; stp >>= 1) {
        if (t < stp) s[t] += s[t + stp];
        __syncthreads();
    }
    if (t == 0) blocksum[blockIdx.x] = s[0];
}

// exclusive scan of blocksum[nblk] (nblk <= 1024), single block
__global__ void scan_b_kernel(int* __restrict__ blocksum, int* __restrict__ blockoff, int nblk) {
    __shared__ int s[1024];
    const int t = threadIdx.x;
    int v = (t < nblk) ? blocksum[t] : 0;
    s[t] = v;
    __syncthreads();
    for (int stp = 1; stp < 1024; stp <<= 1) {
        int add = (t >= stp) ? s[t - stp] : 0;
        __syncthreads();
        s[t] += add;
        __syncthreads();
    }
    if (t < nblk) blockoff[t] = s[t] - v;   // exclusive
}

// off[gi] = blockoff[b] + exclusive-scan-within-block; covers gi in [0, N]
__global__ void scan_c_kernel(const int* __restrict__ cnt, const int* __restrict__ blockoff,
                              int* __restrict__ off, int N) {
    __shared__ int s[256];
    const int t = threadIdx.x;
    const int gi = blockIdx.x * 256 + t;
    int v = (gi < N) ? cnt[gi] : 0;
    s[t] = v;
    __syncthreads();
    for (int stp = 1; stp < 256; stp <<= 1) {
        int add = (t >= stp) ? s[t - stp] : 0;
        __syncthreads();
        s[t] += add;
        __syncthreads();
    }
    if (gi <= N) off[gi] = blockoff[blockIdx.x] + s[t] - v;   // exclusive
}

__global__ void fill_kernel(const int* __restrict__ src, const int* __restrict__ dst,
                            const int* __restrict__ off, int* __restrict__ cursor,
                            int* __restrict__ nbr, int E) {
    int e = blockIdx.x * blockDim.x + threadIdx.x;
    if (e >= E) return;
    const int d = dst[e];
    const int p = atomicAdd(&cursor[d], 1);
    nbr[off[d] + p] = src[e];
}

// ===========================================================================
// W prep: split [W1_l | W1_r]^T into hi/lo bf16: WT[n][k], n=0..127, k=0..255
// ===========================================================================
__global__ void wprep_kernel(const float* __restrict__ Wl, const float* __restrict__ Wr,
                             short* __restrict__ WTh, short* __restrict__ WTl) {
    const int k = threadIdx.x;   // 0..255
    const int n = blockIdx.x;    // 0..127
    const float v = (n < 64) ? Wl[k * 64 + n] : Wr[k * 64 + (n - 64)];
    const short hi = f2bf(v);
    const short lo = f2bf(v - bf2f(hi));
    WTh[n * 256 + k] = hi;
    WTl[n * 256 + k] = lo;
}

// ===========================================================================
// GEMM1 (split-bf16 MFMA): y[N,128] = x[N,256] @ [W1_l | W1_r], fp32-accurate.
// ===========================================================================
#define XS_LD 40   // 32 + 8 pad (bf16 elems); row stride 80 B, 16B aligned
__global__ __launch_bounds__(256) void gemm1_mfma(
    const float* __restrict__ x, const short* __restrict__ WTh,
    const short* __restrict__ WTl, float* __restrict__ y, int N)
{
    __shared__ short xsh[64 * XS_LD];
    __shared__ short xsl[64 * XS_LD];
    __shared__ short wth[128 * XS_LD];
    __shared__ short wtl[128 * XS_LD];

    const int tid  = threadIdx.x;
    const int wave = tid >> 6;
    const int lane = tid & 63;
    const int lm   = lane & 15;
    const int quad = lane >> 4;
    const int brow = blockIdx.x * 64;

    f32x4 acc[4][2];
    #pragma unroll
    for (int mt = 0; mt < 4; ++mt)
        #pragma unroll
        for (int nt = 0; nt < 2; ++nt)
            acc[mt][nt] = (f32x4){0.f, 0.f, 0.f, 0.f};

    const int xr  = tid >> 2;            // 0..63
    const int xkp = (tid & 3) * 8;       // 0/8/16/24
    const int wn  = tid >> 1;            // 0..127
    const int wkp = (tid & 1) * 16;      // 0/16

    for (int kc = 0; kc < DIN; kc += 32) {
        {
            const int row_g = brow + xr;
            float4 f0, f1;
            if (row_g < N) {
                const float4* xp = (const float4*)(x + (size_t)row_g * DIN + kc + xkp);
                f0 = xp[0]; f1 = xp[1];
            } else {
                f0 = f1 = make_float4(0.f, 0.f, 0.f, 0.f);
            }
            bf16x8 ph, pl;
            float fv[8] = {f0.x, f0.y, f0.z, f0.w, f1.x, f1.y, f1.z, f1.w};
            #pragma unroll
            for (int j = 0; j < 8; ++j) {
                const short hi = f2bf(fv[j]);
                ph[j] = hi;
                pl[j] = f2bf(fv[j] - bf2f(hi));
            }
            *(bf16x8*)(&xsh[xr * XS_LD + xkp]) = ph;
            *(bf16x8*)(&xsl[xr * XS_LD + xkp]) = pl;
        }
        {
            const size_t gw = (size_t)wn * 256 + kc + wkp;
            const bf16x8* wph = (const bf16x8*)(WTh + gw);
            const bf16x8* wpl = (const bf16x8*)(WTl + gw);
            *(bf16x8*)(&wth[wn * XS_LD + wkp])     = wph[0];
            *(bf16x8*)(&wth[wn * XS_LD + wkp + 8]) = wph[1];
            *(bf16x8*)(&wtl[wn * XS_LD + wkp])     = wpl[0];
            *(bf16x8*)(&wtl[wn * XS_LD + wkp + 8]) = wpl[1];
        }
        __syncthreads();

        bf16x8 ah[4], al[4], bh[2], bl[2];
        #pragma unroll
        for (int mt = 0; mt < 4; ++mt) {
            const int off2 = (mt * 16 + lm) * XS_LD + quad * 8;
            ah[mt] = *(const bf16x8*)(&xsh[off2]);
            al[mt] = *(const bf16x8*)(&xsl[off2]);
        }
        #pragma unroll
        for (int nt = 0; nt < 2; ++nt) {
            const int off2 = (wave * 32 + nt * 16 + lm) * XS_LD + quad * 8;
            bh[nt] = *(const bf16x8*)(&wth[off2]);
            bl[nt] = *(const bf16x8*)(&wtl[off2]);
        }
        #pragma unroll
        for (int mt = 0; mt < 4; ++mt)
            #pragma unroll
            for (int nt = 0; nt < 2; ++nt) {
                acc[mt][nt] = __builtin_amdgcn_mfma_f32_16x16x32_bf16(
                    ah[mt], bh[nt], acc[mt][nt], 0, 0, 0);
                acc[mt][nt] = __builtin_amdgcn_mfma_f32_16x16x32_bf16(
                    ah[mt], bl[nt], acc[mt][nt], 0, 0, 0);
                acc[mt][nt] = __builtin_amdgcn_mfma_f32_16x16x32_bf16(
                    al[mt], bh[nt], acc[mt][nt], 0, 0, 0);
            }
        __syncthreads();
    }

    #pragma unroll
    for (int mt = 0; mt < 4; ++mt) {
        #pragma unroll
        for (int r = 0; r < 4; ++r) {
            const int row_g = brow + mt * 16 + quad * 4 + r;
            if (row_g < N) {
                const int col = wave * 32 + lm;
                float* yp = y + (size_t)row_g * 128 + col;
                yp[0]  = acc[mt][0][r];
                yp[16] = acc[mt][1][r];
            }
        }
    }
}

// ===========================================================================
// fused1: per node (one wave each):
//   agg = mean_{s in N(i)} y_l[s]; v = agg + b1 + y_r[i]; h = relu(normalize(v));
//   z[i] = [h @ W2_l | h @ W2_r]
// ===========================================================================
__global__ __launch_bounds__(256) void fused1_kernel(
    const float* __restrict__ y, const int* __restrict__ off, const int* __restrict__ nbr,
    const float* __restrict__ b1, const float* __restrict__ W2l, const float* __restrict__ W2r,
    float* __restrict__ z, int N)
{
    const int wave = threadIdx.x >> 6;
    const int lane = threadIdx.x & 63;
    const int i = blockIdx.x * 4 + wave;
    if (i >= N) return;

    const int beg = off[i];
    const int end = off[i + 1];

    float acc = 0.f;
    for (int j = beg; j < end; ++j) {
        const int s = nbr[j];
        acc += y[(size_t)s * 128 + lane];
    }
    const float dinv = 1.0f / fmaxf((float)(end - beg), 1.0f);
    float v = acc * dinv + b1[lane] + y[(size_t)i * 128 + 64 + lane];

    // wave L2-norm
    float ss = v * v;
    #pragma unroll
    for (int m = 32; m >= 1; m >>= 1) ss += __shfl_xor(ss, m, 64);
    const float inv = 1.0f / fmaxf(sqrtf(ss), 1e-12f);
    const float hv = fmaxf(v * inv, 0.f);

    // gemm2 inline: lane f holds h[f]; W2l/W2r are [64][4]
    const float4 wl = *(const float4*)(W2l + lane * 4);
    const float4 wr = *(const float4*)(W2r + lane * 4);
    float p[8] = {hv * wl.x, hv * wl.y, hv * wl.z, hv * wl.w,
                  hv * wr.x, hv * wr.y, hv * wr.z, hv * wr.w};
    #pragma unroll
    for (int c = 0; c < 8; ++c) {
        #pragma unroll
        for (int m = 32; m >= 1; m >>= 1) p[c] += __shfl_xor(p[c], m, 64);
    }
    if (lane == 0) {
        float* zp = z + (size_t)i * 8;
        *(float4*)(zp)     = make_float4(p[0], p[1], p[2], p[3]);
        *(float4*)(zp + 4) = make_float4(p[4], p[5], p[6], p[7]);
    }
}

// ===========================================================================
// fused2: per node (one thread): out = normalize(mean z_l[nbr] + b2 + z_r[i])
// ===========================================================================
__global__ void fused2_kernel(const float* __restrict__ z, const int* __restrict__ off,
                              const int* __restrict__ nbr, const float* __restrict__ b2,
                              float* __restrict__ out, int N)
{
    const int i = blockIdx.x * blockDim.x + threadIdx.x;
    if (i >= N) return;
    const int beg = off[i];
    const int end = off[i + 1];
    float4 acc = make_float4(0.f, 0.f, 0.f, 0.f);
    for (int j = beg; j < end; ++j) {
        const int s = nbr[j];
        const float4 t = *(const float4*)(z + (size_t)s * 8);
        acc.x += t.x; acc.y += t.y; acc.z += t.z; acc.w += t.w;
    }
    const float dinv = 1.0f / fmaxf((float)(end - beg), 1.0f);
    const float4 r  = *(const float4*)(z + (size_t)i * 8 + 4);
    const float4 bb = *(const float4*)(b2);
    float4 o;
    o.x = acc.x * dinv + bb.x + r.x;
    o.y = acc.y * dinv + bb.y + r.y;
    o.z = acc.z * dinv + bb.z + r.z;
    o.w = acc.w * dinv + bb.w + r.w;
    const float ss = o.x * o.x + o.y * o.y + o.z * o.z + o.w * o.w;
    const float inv = 1.0f / fmaxf(sqrtf(ss), 1e-12f);
    o.x *= inv; o.y *= inv; o.z *= inv; o.w *= inv;
    *(float4*)(out + (size_t)i * 4) = o;
}

// ===========================================================================
extern "C" void kernel_launch(void* const* d_in, const int* in_sizes, int n_in,
                              void* d_out, int out_size, void* d_ws, size_t ws_size,
                              hipStream_t stream)
{
    const float* x    = (const float*)d_in[0];
    const int*   ei   = (const int*)d_in[1];
    const float* W1l  = (const float*)d_in[2];
    const float* b1l  = (const float*)d_in[3];
    const float* W1r  = (const float*)d_in[4];
    const float* W2l  = (const float*)d_in[5];
    const float* b2l  = (const float*)d_in[6];
    const float* W2r  = (const float*)d_in[7];
    float* out = (float*)d_out;

    const int N = in_sizes[0] / DIN;
    const int E = in_sizes[1] / 2;
    const int* src = ei;
    const int* dst = ei + E;
    const int nblk = (N + 255) / 256;

    // workspace layout
    char* ws = (char*)d_ws;
    size_t woff = 0;
    auto alloc = [&](size_t bytes) {
        void* p = ws + woff;
        woff += (bytes + 255) & ~(size_t)255;
        return p;
    };
    float* y        = (float*)alloc((size_t)N * 128 * 4);
    float* z        = (float*)alloc((size_t)N * 8 * 4);
    short* WTh      = (short*)alloc((size_t)128 * 256 * 2);
    short* WTl      = (short*)alloc((size_t)128 * 256 * 2);
    int*   cnt      = (int*)alloc((size_t)N * 4);
    int*   cursor   = (int*)alloc((size_t)N * 4);
    int*   off      = (int*)alloc((size_t)(N + 1) * 4);
    int*   nbr      = (int*)alloc((size_t)E * 4);
    int*   blocksum = (int*)alloc((size_t)nblk * 4);
    int*   blockoff = (int*)alloc((size_t)nblk * 4);

    hipMemsetAsync(cnt,    0, (size_t)N * 4, stream);
    hipMemsetAsync(cursor, 0, (size_t)N * 4, stream);

    // --- CSR build
    count_kernel<<<(E + 255) / 256, 256, 0, stream>>>(dst, cnt, E);
    scan_a_kernel<<<nblk, 256, 0, stream>>>(cnt, blocksum, N);
    scan_b_kernel<<<1, 1024, 0, stream>>>(blocksum, blockoff, nblk);
    scan_c_kernel<<<nblk, 256, 0, stream>>>(cnt, blockoff, off, N);
    fill_kernel<<<(E + 255) / 256, 256, 0, stream>>>(src, dst, off, cursor, nbr, E);

    // --- layer 1 GEMM
    wprep_kernel<<<128, 256, 0, stream>>>(W1l, W1r, WTh, WTl);
    gemm1_mfma<<<(N + 63) / 64, 256, 0, stream>>>(x, WTh, WTl, y, N);

    // --- fused aggregate + norm + relu + gemm2
    fused1_kernel<<<(N + 3) / 4, 256, 0, stream>>>(y, off, nbr, b1l, W2l, W2r, z, N);

    // --- fused aggregate + norm (layer 2)
    fused2_kernel<<<(N + 255) / 256, 256, 0, stream>>>(z, off, nbr, b2l, out, N);
}

// Round 5
// 275.597 us; speedup vs baseline: 1.7687x; 1.0795x over previous
//
#include <hip/hip_runtime.h>

#define DIN 256
#define DH  64
#define DOUT 4

typedef __attribute__((ext_vector_type(8))) short bf16x8;
typedef __attribute__((ext_vector_type(4))) float f32x4;

__device__ __forceinline__ short f2bf(float f) {
    unsigned int u = __float_as_uint(f);
    unsigned int r = (u + 0x7FFFu + ((u >> 16) & 1u)) >> 16;
    return (short)r;
}
__device__ __forceinline__ float bf2f(short h) {
    return __uint_as_float(((unsigned int)(unsigned short)h) << 16);
}

// ===========================================================================
// CSR build: count -> 2-level exclusive scan -> fill
// ===========================================================================
__global__ void count_kernel(const int* __restrict__ dst, int* __restrict__ cnt, int E) {
    int e = blockIdx.x * blockDim.x + threadIdx.x;
    if (e < E) atomicAdd(&cnt[dst[e]], 1);
}

__global__ void scan_a_kernel(const int* __restrict__ cnt, int* __restrict__ blocksum, int N) {
    __shared__ int s[256];
    const int t = threadIdx.x;
    const int gi = blockIdx.x * 256 + t;
    s[t] = (gi < N) ? cnt[gi] : 0;
    __syncthreads();
    for (int stp = 128; stp > 0; stp >>= 1) {
        if (t < stp) s[t] += s[t + stp];
        __syncthreads();
    }
    if (t == 0) blocksum[blockIdx.x] = s[0];
}

__global__ void scan_b_kernel(int* __restrict__ blocksum, int* __restrict__ blockoff, int nblk) {
    __shared__ int s[1024];
    const int t = threadIdx.x;
    int v = (t < nblk) ? blocksum[t] : 0;
    s[t] = v;
    __syncthreads();
    for (int stp = 1; stp < 1024; stp <<= 1) {
        int add = (t >= stp) ? s[t - stp] : 0;
        __syncthreads();
        s[t] += add;
        __syncthreads();
    }
    if (t < nblk) blockoff[t] = s[t] - v;   // exclusive
}

__global__ void scan_c_kernel(const int* __restrict__ cnt, const int* __restrict__ blockoff,
                              int* __restrict__ off, int N) {
    __shared__ int s[256];
    const int t = threadIdx.x;
    const int gi = blockIdx.x * 256 + t;
    int v = (gi < N) ? cnt[gi] : 0;
    s[t] = v;
    __syncthreads();
    for (int stp = 1; stp < 256; stp <<= 1) {
        int add = (t >= stp) ? s[t - stp] : 0;
        __syncthreads();
        s[t] += add;
        __syncthreads();
    }
    if (gi <= N) off[gi] = blockoff[blockIdx.x] + s[t] - v;   // exclusive
}

__global__ void fill_kernel(const int* __restrict__ src, const int* __restrict__ dst,
                            const int* __restrict__ off, int* __restrict__ cursor,
                            int* __restrict__ nbr, int E) {
    int e = blockIdx.x * blockDim.x + threadIdx.x;
    if (e >= E) return;
    const int d = dst[e];
    const int p = atomicAdd(&cursor[d], 1);
    nbr[off[d] + p] = src[e];
}

// ===========================================================================
// W prep: split [W1_l | W1_r]^T into hi/lo bf16: WT[n][k], n=0..127, k=0..255
// ===========================================================================
__global__ void wprep_kernel(const float* __restrict__ Wl, const float* __restrict__ Wr,
                             short* __restrict__ WTh, short* __restrict__ WTl) {
    const int k = threadIdx.x;   // 0..255
    const int n = blockIdx.x;    // 0..127
    const float v = (n < 64) ? Wl[k * 64 + n] : Wr[k * 64 + (n - 64)];
    const short hi = f2bf(v);
    const short lo = f2bf(v - bf2f(hi));
    WTh[n * 256 + k] = hi;
    WTl[n * 256 + k] = lo;
}

// ===========================================================================
// GEMM1 (split-bf16 MFMA): y[N,128] = x[N,256] @ [W1_l | W1_r], fp32-accurate.
// ===========================================================================
#define XS_LD 40   // 32 + 8 pad (bf16 elems); row stride 80 B, 16B aligned
__global__ __launch_bounds__(256) void gemm1_mfma(
    const float* __restrict__ x, const short* __restrict__ WTh,
    const short* __restrict__ WTl, float* __restrict__ y, int N)
{
    __shared__ short xsh[64 * XS_LD];
    __shared__ short xsl[64 * XS_LD];
    __shared__ short wth[128 * XS_LD];
    __shared__ short wtl[128 * XS_LD];

    const int tid  = threadIdx.x;
    const int wave = tid >> 6;
    const int lane = tid & 63;
    const int lm   = lane & 15;
    const int quad = lane >> 4;
    const int brow = blockIdx.x * 64;

    f32x4 acc[4][2];
    #pragma unroll
    for (int mt = 0; mt < 4; ++mt)
        #pragma unroll
        for (int nt = 0; nt < 2; ++nt)
            acc[mt][nt] = (f32x4){0.f, 0.f, 0.f, 0.f};

    const int xr  = tid >> 2;            // 0..63
    const int xkp = (tid & 3) * 8;       // 0/8/16/24
    const int wn  = tid >> 1;            // 0..127
    const int wkp = (tid & 1) * 16;      // 0/16

    for (int kc = 0; kc < DIN; kc += 32) {
        {
            const int row_g = brow + xr;
            float4 f0, f1;
            if (row_g < N) {
                const float4* xp = (const float4*)(x + (size_t)row_g * DIN + kc + xkp);
                f0 = xp[0]; f1 = xp[1];
            } else {
                f0 = f1 = make_float4(0.f, 0.f, 0.f, 0.f);
            }
            bf16x8 ph, pl;
            float fv[8] = {f0.x, f0.y, f0.z, f0.w, f1.x, f1.y, f1.z, f1.w};
            #pragma unroll
            for (int j = 0; j < 8; ++j) {
                const short hi = f2bf(fv[j]);
                ph[j] = hi;
                pl[j] = f2bf(fv[j] - bf2f(hi));
            }
            *(bf16x8*)(&xsh[xr * XS_LD + xkp]) = ph;
            *(bf16x8*)(&xsl[xr * XS_LD + xkp]) = pl;
        }
        {
            const size_t gw = (size_t)wn * 256 + kc + wkp;
            const bf16x8* wph = (const bf16x8*)(WTh + gw);
            const bf16x8* wpl = (const bf16x8*)(WTl + gw);
            *(bf16x8*)(&wth[wn * XS_LD + wkp])     = wph[0];
            *(bf16x8*)(&wth[wn * XS_LD + wkp + 8]) = wph[1];
            *(bf16x8*)(&wtl[wn * XS_LD + wkp])     = wpl[0];
            *(bf16x8*)(&wtl[wn * XS_LD + wkp + 8]) = wpl[1];
        }
        __syncthreads();

        bf16x8 ah[4], al[4], bh[2], bl[2];
        #pragma unroll
        for (int mt = 0; mt < 4; ++mt) {
            const int off2 = (mt * 16 + lm) * XS_LD + quad * 8;
            ah[mt] = *(const bf16x8*)(&xsh[off2]);
            al[mt] = *(const bf16x8*)(&xsl[off2]);
        }
        #pragma unroll
        for (int nt = 0; nt < 2; ++nt) {
            const int off2 = (wave * 32 + nt * 16 + lm) * XS_LD + quad * 8;
            bh[nt] = *(const bf16x8*)(&wth[off2]);
            bl[nt] = *(const bf16x8*)(&wtl[off2]);
        }
        #pragma unroll
        for (int mt = 0; mt < 4; ++mt)
            #pragma unroll
            for (int nt = 0; nt < 2; ++nt) {
                acc[mt][nt] = __builtin_amdgcn_mfma_f32_16x16x32_bf16(
                    ah[mt], bh[nt], acc[mt][nt], 0, 0, 0);
                acc[mt][nt] = __builtin_amdgcn_mfma_f32_16x16x32_bf16(
                    ah[mt], bl[nt], acc[mt][nt], 0, 0, 0);
                acc[mt][nt] = __builtin_amdgcn_mfma_f32_16x16x32_bf16(
                    al[mt], bh[nt], acc[mt][nt], 0, 0, 0);
            }
        __syncthreads();
    }

    #pragma unroll
    for (int mt = 0; mt < 4; ++mt) {
        #pragma unroll
        for (int r = 0; r < 4; ++r) {
            const int row_g = brow + mt * 16 + quad * 4 + r;
            if (row_g < N) {
                const int col = wave * 32 + lm;
                float* yp = y + (size_t)row_g * 128 + col;
                yp[0]  = acc[mt][0][r];
                yp[16] = acc[mt][1][r];
            }
        }
    }
}

// ===========================================================================
// fused1: per node (one wave each):
//   agg = mean_{s in N(i)} y_l[s]; v = agg + b1 + y_r[i]; h = relu(normalize(v));
//   z[i] = [h @ W2_l | h @ W2_r]
// ===========================================================================
__global__ __launch_bounds__(256) void fused1_kernel(
    const float* __restrict__ y, const int* __restrict__ off, const int* __restrict__ nbr,
    const float* __restrict__ b1, const float* __restrict__ W2l, const float* __restrict__ W2r,
    float* __restrict__ z, int N)
{
    const int wave = threadIdx.x >> 6;
    const int lane = threadIdx.x & 63;
    const int i = blockIdx.x * 4 + wave;
    if (i >= N) return;

    const int beg = off[i];
    const int end = off[i + 1];
    const int deg = end - beg;

    // lane-parallel prefetch of neighbor indices (one coalesced load), then
    // broadcast with __shfl so the y-row gathers pipeline.
    const int dd = (deg < 64) ? deg : 64;
    int myn = (lane < dd) ? nbr[beg + lane] : 0;

    float acc = 0.f;
    int j = 0;
    for (; j + 1 < dd; j += 2) {
        const int s0 = __shfl(myn, j, 64);
        const int s1 = __shfl(myn, j + 1, 64);
        const float v0 = y[(size_t)s0 * 128 + lane];
        const float v1 = y[(size_t)s1 * 128 + lane];
        acc += v0 + v1;
    }
    if (j < dd) {
        const int s0 = __shfl(myn, j, 64);
        acc += y[(size_t)s0 * 128 + lane];
    }
    // rare tail: deg > 64
    for (int q = beg + 64; q < end; ++q) {
        const int s = nbr[q];
        acc += y[(size_t)s * 128 + lane];
    }

    const float dinv = 1.0f / fmaxf((float)deg, 1.0f);
    float v = acc * dinv + b1[lane] + y[(size_t)i * 128 + 64 + lane];

    // wave L2-norm (6 shuffles)
    float ss = v * v;
    #pragma unroll
    for (int m = 32; m >= 1; m >>= 1) ss += __shfl_xor(ss, m, 64);
    const float inv = 1.0f / fmaxf(sqrtf(ss), 1e-12f);
    const float hv = fmaxf(v * inv, 0.f);

    // gemm2 inline: lane f holds h[f]; W2l/W2r are [64][4]
    const float4 wl = *(const float4*)(W2l + lane * 4);
    const float4 wr = *(const float4*)(W2r + lane * 4);
    float p0 = hv * wl.x, p1 = hv * wl.y, p2 = hv * wl.z, p3 = hv * wl.w;
    float p4 = hv * wr.x, p5 = hv * wr.y, p6 = hv * wr.z, p7 = hv * wr.w;

    // multi-channel butterfly: 8 channels over 64 lanes in 10 shuffles.
    // step 1 (xor 1): keep 4 channels by bit0, exchange the other 4
    const bool b0 = (lane & 1) != 0;
    float s0_ = b0 ? p0 : p4;
    float s1_ = b0 ? p1 : p5;
    float s2_ = b0 ? p2 : p6;
    float s3_ = b0 ? p3 : p7;
    float q0 = (b0 ? p4 : p0) + __shfl_xor(s0_, 1, 64);
    float q1 = (b0 ? p5 : p1) + __shfl_xor(s1_, 1, 64);
    float q2 = (b0 ? p6 : p2) + __shfl_xor(s2_, 1, 64);
    float q3 = (b0 ? p7 : p3) + __shfl_xor(s3_, 1, 64);
    // step 2 (xor 2): keep 2 by bit1
    const bool b1b = (lane & 2) != 0;
    float t0 = b1b ? q0 : q2;
    float t1 = b1b ? q1 : q3;
    float r0 = (b1b ? q2 : q0) + __shfl_xor(t0, 2, 64);
    float r1 = (b1b ? q3 : q1) + __shfl_xor(t1, 2, 64);
    // step 3 (xor 4): keep 1 by bit2
    const bool b2 = (lane & 4) != 0;
    float u0 = b2 ? r0 : r1;
    float zv = (b2 ? r1 : r0) + __shfl_xor(u0, 4, 64);
    // cross-group reduction over 8-lane groups
    zv += __shfl_xor(zv, 8, 64);
    zv += __shfl_xor(zv, 16, 64);
    zv += __shfl_xor(zv, 32, 64);
    // lane -> channel: c = 4*b0 + 2*b1 + b2  (3-bit reversal)
    const int ch = 4 * (lane & 1) + ((lane & 2)) + ((lane >> 2) & 1);
    if (lane < 8) z[(size_t)i * 8 + ch] = zv;
}

// ===========================================================================
// fused2: per node (one thread): out = normalize(mean z_l[nbr] + b2 + z_r[i])
// ===========================================================================
__global__ void fused2_kernel(const float* __restrict__ z, const int* __restrict__ off,
                              const int* __restrict__ nbr, const float* __restrict__ b2,
                              float* __restrict__ out, int N)
{
    const int i = blockIdx.x * blockDim.x + threadIdx.x;
    if (i >= N) return;
    const int beg = off[i];
    const int end = off[i + 1];
    float4 acc = make_float4(0.f, 0.f, 0.f, 0.f);
    for (int j = beg; j < end; ++j) {
        const int s = nbr[j];
        const float4 t = *(const float4*)(z + (size_t)s * 8);
        acc.x += t.x; acc.y += t.y; acc.z += t.z; acc.w += t.w;
    }
    const float dinv = 1.0f / fmaxf((float)(end - beg), 1.0f);
    const float4 r  = *(const float4*)(z + (size_t)i * 8 + 4);
    const float4 bb = *(const float4*)(b2);
    float4 o;
    o.x = acc.x * dinv + bb.x + r.x;
    o.y = acc.y * dinv + bb.y + r.y;
    o.z = acc.z * dinv + bb.z + r.z;
    o.w = acc.w * dinv + bb.w + r.w;
    const float ss = o.x * o.x + o.y * o.y + o.z * o.z + o.w * o.w;
    const float inv = 1.0f / fmaxf(sqrtf(ss), 1e-12f);
    o.x *= inv; o.y *= inv; o.z *= inv; o.w *= inv;
    *(float4*)(out + (size_t)i * 4) = o;
}

// ===========================================================================
extern "C" void kernel_launch(void* const* d_in, const int* in_sizes, int n_in,
                              void* d_out, int out_size, void* d_ws, size_t ws_size,
                              hipStream_t stream)
{
    const float* x    = (const float*)d_in[0];
    const int*   ei   = (const int*)d_in[1];
    const float* W1l  = (const float*)d_in[2];
    const float* b1l  = (const float*)d_in[3];
    const float* W1r  = (const float*)d_in[4];
    const float* W2l  = (const float*)d_in[5];
    const float* b2l  = (const float*)d_in[6];
    const float* W2r  = (const float*)d_in[7];
    float* out = (float*)d_out;

    const int N = in_sizes[0] / DIN;
    const int E = in_sizes[1] / 2;
    const int* src = ei;
    const int* dst = ei + E;
    const int nblk = (N + 255) / 256;

    // workspace layout
    char* ws = (char*)d_ws;
    size_t woff = 0;
    auto alloc = [&](size_t bytes) {
        void* p = ws + woff;
        woff += (bytes + 255) & ~(size_t)255;
        return p;
    };
    float* y        = (float*)alloc((size_t)N * 128 * 4);
    float* z        = (float*)alloc((size_t)N * 8 * 4);
    short* WTh      = (short*)alloc((size_t)128 * 256 * 2);
    short* WTl      = (short*)alloc((size_t)128 * 256 * 2);
    int*   cnt      = (int*)alloc((size_t)N * 4);
    int*   cursor   = (int*)alloc((size_t)N * 4);
    int*   off      = (int*)alloc((size_t)(N + 1) * 4);
    int*   nbr      = (int*)alloc((size_t)E * 4);
    int*   blocksum = (int*)alloc((size_t)nblk * 4);
    int*   blockoff = (int*)alloc((size_t)nblk * 4);

    hipMemsetAsync(cnt,    0, (size_t)N * 4, stream);
    hipMemsetAsync(cursor, 0, (size_t)N * 4, stream);

    // --- CSR build
    count_kernel<<<(E + 255) / 256, 256, 0, stream>>>(dst, cnt, E);
    scan_a_kernel<<<nblk, 256, 0, stream>>>(cnt, blocksum, N);
    scan_b_kernel<<<1, 1024, 0, stream>>>(blocksum, blockoff, nblk);
    scan_c_kernel<<<nblk, 256, 0, stream>>>(cnt, blockoff, off, N);
    fill_kernel<<<(E + 255) / 256, 256, 0, stream>>>(src, dst, off, cursor, nbr, E);

    // --- layer 1 GEMM
    wprep_kernel<<<128, 256, 0, stream>>>(W1l, W1r, WTh, WTl);
    gemm1_mfma<<<(N + 63) / 64, 256, 0, stream>>>(x, WTh, WTl, y, N);

    // --- fused aggregate + norm + relu + gemm2
    fused1_kernel<<<(N + 3) / 4, 256, 0, stream>>>(y, off, nbr, b1l, W2l, W2r, z, N);

    // --- fused aggregate + norm (layer 2)
    fused2_kernel<<<(N + 255) / 256, 256, 0, stream>>>(z, off, nbr, b2l, out, N);
}

// Round 6
// 273.540 us; speedup vs baseline: 1.7820x; 1.0075x over previous
//
#include <hip/hip_runtime.h>

#define DIN 256
#define DH  64
#define DOUT 4

typedef __attribute__((ext_vector_type(8))) short bf16x8;
typedef __attribute__((ext_vector_type(4))) float f32x4;

__device__ __forceinline__ short f2bf(float f) {       // RNE (used in wprep only)
    unsigned int u = __float_as_uint(f);
    unsigned int r = (u + 0x7FFFu + ((u >> 16) & 1u)) >> 16;
    return (short)r;
}
__device__ __forceinline__ short f2bf_trunc(float f) { // truncate mantissa
    return (short)(__float_as_uint(f) >> 16);
}
__device__ __forceinline__ float bf2f(short h) {
    return __uint_as_float(((unsigned int)(unsigned short)h) << 16);
}

// ===========================================================================
// CSR build: count -> 2-level exclusive scan -> fill
// ===========================================================================
__global__ void count_kernel(const int* __restrict__ dst, int* __restrict__ cnt, int E) {
    int e = blockIdx.x * blockDim.x + threadIdx.x;
    if (e < E) atomicAdd(&cnt[dst[e]], 1);
}

__global__ void scan_a_kernel(const int* __restrict__ cnt, int* __restrict__ blocksum, int N) {
    __shared__ int s[256];
    const int t = threadIdx.x;
    const int gi = blockIdx.x * 256 + t;
    s[t] = (gi < N) ? cnt[gi] : 0;
    __syncthreads();
    for (int stp = 128; stp > 0; stp >>= 1) {
        if (t < stp) s[t] += s[t + stp];
        __syncthreads();
    }
    if (t == 0) blocksum[blockIdx.x] = s[0];
}

__global__ void scan_b_kernel(int* __restrict__ blocksum, int* __restrict__ blockoff, int nblk) {
    __shared__ int s[1024];
    const int t = threadIdx.x;
    int v = (t < nblk) ? blocksum[t] : 0;
    s[t] = v;
    __syncthreads();
    for (int stp = 1; stp < 1024; stp <<= 1) {
        int add = (t >= stp) ? s[t - stp] : 0;
        __syncthreads();
        s[t] += add;
        __syncthreads();
    }
    if (t < nblk) blockoff[t] = s[t] - v;   // exclusive
}

__global__ void scan_c_kernel(const int* __restrict__ cnt, const int* __restrict__ blockoff,
                              int* __restrict__ off, int N) {
    __shared__ int s[256];
    const int t = threadIdx.x;
    const int gi = blockIdx.x * 256 + t;
    int v = (gi < N) ? cnt[gi] : 0;
    s[t] = v;
    __syncthreads();
    for (int stp = 1; stp < 256; stp <<= 1) {
        int add = (t >= stp) ? s[t - stp] : 0;
        __syncthreads();
        s[t] += add;
        __syncthreads();
    }
    if (gi <= N) off[gi] = blockoff[blockIdx.x] + s[t] - v;   // exclusive
}

__global__ void fill_kernel(const int* __restrict__ src, const int* __restrict__ dst,
                            const int* __restrict__ off, int* __restrict__ cursor,
                            int* __restrict__ nbr, int E) {
    int e = blockIdx.x * blockDim.x + threadIdx.x;
    if (e >= E) return;
    const int d = dst[e];
    const int p = atomicAdd(&cursor[d], 1);
    nbr[off[d] + p] = src[e];
}

// ===========================================================================
// W prep: split [W1_l | W1_r]^T into hi/lo bf16: WT[n][k], n=0..127, k=0..255
// ===========================================================================
__global__ void wprep_kernel(const float* __restrict__ Wl, const float* __restrict__ Wr,
                             short* __restrict__ WTh, short* __restrict__ WTl) {
    const int k = threadIdx.x;   // 0..255
    const int n = blockIdx.x;    // 0..127
    const float v = (n < 64) ? Wl[k * 64 + n] : Wr[k * 64 + (n - 64)];
    const short hi = f2bf(v);
    const short lo = f2bf(v - bf2f(hi));
    WTh[n * 256 + k] = hi;
    WTl[n * 256 + k] = lo;
}

// ===========================================================================
// GEMM1 (split-bf16 MFMA): y[N,128] = x[N,256] @ [W1_l | W1_r], fp32-accurate.
// v2: W fragments in registers (prefetched from L2-resident WTh/WTl);
//     x-only LDS, double-buffered; one barrier per K-chunk.
// Block: 64 rows x 128 cols, BK=32, 256 threads (4 waves).
// Wave w owns cols [w*32, w*32+32): 4 M-tiles x 2 N-tiles of 16x16x32 MFMA.
// ===========================================================================
#define XS_LD 40   // 32 + 8 pad (bf16 elems); 80 B row stride (16B-aligned, 20 banks)
__global__ __launch_bounds__(256, 4) void gemm1_mfma(
    const float* __restrict__ x, const short* __restrict__ WTh,
    const short* __restrict__ WTl, float* __restrict__ y, int N)
{
    __shared__ short xsh[2][64 * XS_LD];   // 2 x 5120 B
    __shared__ short xsl[2][64 * XS_LD];

    const int tid  = threadIdx.x;
    const int wave = tid >> 6;
    const int lane = tid & 63;
    const int lm   = lane & 15;
    const int quad = lane >> 4;
    const int brow = blockIdx.x * 64;

    // ---- x staging indices: thread stages 8 elems of one row per chunk
    const int xr    = tid >> 2;           // 0..63
    const int xk    = (tid & 3) * 8;      // 0/8/16/24
    const int row_g = brow + xr;
    const bool xvalid = (row_g < N);
    const float* xptr = x + (size_t)row_g * DIN + xk;
    const int xs_off = xr * XS_LD + xk;

    // ---- W fragment global offsets (per lane, per N-tile)
    const int col0 = wave * 32 + lm;
    const size_t wb0 = (size_t)col0 * 256 + quad * 8;
    const size_t wb1 = (size_t)(col0 + 16) * 256 + quad * 8;

    f32x4 acc[4][2];
    #pragma unroll
    for (int mt = 0; mt < 4; ++mt)
        #pragma unroll
        for (int nt = 0; nt < 2; ++nt)
            acc[mt][nt] = (f32x4){0.f, 0.f, 0.f, 0.f};

    // ---- prologue: stage chunk 0, load W chunk 0
    {
        float4 a, b;
        if (xvalid) {
            a = ((const float4*)xptr)[0];
            b = ((const float4*)xptr)[1];
        } else {
            a = b = make_float4(0.f, 0.f, 0.f, 0.f);
        }
        bf16x8 ph, pl;
        float fv[8] = {a.x, a.y, a.z, a.w, b.x, b.y, b.z, b.w};
        #pragma unroll
        for (int j = 0; j < 8; ++j) {
            const short hi = f2bf_trunc(fv[j]);
            ph[j] = hi;
            pl[j] = f2bf_trunc(fv[j] - bf2f(hi));
        }
        *(bf16x8*)(&xsh[0][xs_off]) = ph;
        *(bf16x8*)(&xsl[0][xs_off]) = pl;
    }
    bf16x8 wh_cur[2], wl_cur[2];
    wh_cur[0] = *(const bf16x8*)(WTh + wb0);
    wh_cur[1] = *(const bf16x8*)(WTh + wb1);
    wl_cur[0] = *(const bf16x8*)(WTl + wb0);
    wl_cur[1] = *(const bf16x8*)(WTl + wb1);
    __syncthreads();

    #pragma unroll
    for (int k = 0; k < 8; ++k) {
        const int buf = k & 1;

        // ---- prefetch chunk k+1 (global loads issue now, consumed after MFMA)
        float4 na, nb;
        bf16x8 wh_nxt[2], wl_nxt[2];
        if (k < 7) {
            const int kc = (k + 1) * 32;
            if (xvalid) {
                na = ((const float4*)(xptr + kc))[0];
                nb = ((const float4*)(xptr + kc))[1];
            } else {
                na = nb = make_float4(0.f, 0.f, 0.f, 0.f);
            }
            wh_nxt[0] = *(const bf16x8*)(WTh + wb0 + kc);
            wh_nxt[1] = *(const bf16x8*)(WTh + wb1 + kc);
            wl_nxt[0] = *(const bf16x8*)(WTl + wb0 + kc);
            wl_nxt[1] = *(const bf16x8*)(WTl + wb1 + kc);
        }

        // ---- compute on chunk k
        #pragma unroll
        for (int mt = 0; mt < 4; ++mt) {
            const int aoff = (mt * 16 + lm) * XS_LD + quad * 8;
            const bf16x8 ah = *(const bf16x8*)(&xsh[buf][aoff]);
            const bf16x8 al = *(const bf16x8*)(&xsl[buf][aoff]);
            #pragma unroll
            for (int nt = 0; nt < 2; ++nt) {
                acc[mt][nt] = __builtin_amdgcn_mfma_f32_16x16x32_bf16(
                    ah, wh_cur[nt], acc[mt][nt], 0, 0, 0);
                acc[mt][nt] = __builtin_amdgcn_mfma_f32_16x16x32_bf16(
                    ah, wl_cur[nt], acc[mt][nt], 0, 0, 0);
                acc[mt][nt] = __builtin_amdgcn_mfma_f32_16x16x32_bf16(
                    al, wh_cur[nt], acc[mt][nt], 0, 0, 0);
            }
        }

        // ---- convert + store chunk k+1, rotate W regs
        if (k < 7) {
            bf16x8 ph, pl;
            float fv[8] = {na.x, na.y, na.z, na.w, nb.x, nb.y, nb.z, nb.w};
            #pragma unroll
            for (int j = 0; j < 8; ++j) {
                const short hi = f2bf_trunc(fv[j]);
                ph[j] = hi;
                pl[j] = f2bf_trunc(fv[j] - bf2f(hi));
            }
            *(bf16x8*)(&xsh[buf ^ 1][xs_off]) = ph;
            *(bf16x8*)(&xsl[buf ^ 1][xs_off]) = pl;
            #pragma unroll
            for (int nt = 0; nt < 2; ++nt) {
                wh_cur[nt] = wh_nxt[nt];
                wl_cur[nt] = wl_nxt[nt];
            }
            __syncthreads();
        }
    }

    // ---- epilogue: C/D layout col=lane&15, row=quad*4+reg
    #pragma unroll
    for (int mt = 0; mt < 4; ++mt) {
        #pragma unroll
        for (int r = 0; r < 4; ++r) {
            const int rg = brow + mt * 16 + quad * 4 + r;
            if (rg < N) {
                const int col = wave * 32 + lm;
                float* yp = y + (size_t)rg * 128 + col;
                yp[0]  = acc[mt][0][r];
                yp[16] = acc[mt][1][r];
            }
        }
    }
}

// ===========================================================================
// fused1: per node (one wave each):
//   agg = mean_{s in N(i)} y_l[s]; v = agg + b1 + y_r[i]; h = relu(normalize(v));
//   z[i] = [h @ W2_l | h @ W2_r]
// ===========================================================================
__global__ __launch_bounds__(256) void fused1_kernel(
    const float* __restrict__ y, const int* __restrict__ off, const int* __restrict__ nbr,
    const float* __restrict__ b1, const float* __restrict__ W2l, const float* __restrict__ W2r,
    float* __restrict__ z, int N)
{
    const int wave = threadIdx.x >> 6;
    const int lane = threadIdx.x & 63;
    const int i = blockIdx.x * 4 + wave;
    if (i >= N) return;

    const int beg = off[i];
    const int end = off[i + 1];
    const int deg = end - beg;

    // lane-parallel prefetch of neighbor indices (one coalesced load), then
    // broadcast with __shfl so the y-row gathers pipeline.
    const int dd = (deg < 64) ? deg : 64;
    int myn = (lane < dd) ? nbr[beg + lane] : 0;

    float acc = 0.f;
    int j = 0;
    for (; j + 1 < dd; j += 2) {
        const int s0 = __shfl(myn, j, 64);
        const int s1 = __shfl(myn, j + 1, 64);
        const float v0 = y[(size_t)s0 * 128 + lane];
        const float v1 = y[(size_t)s1 * 128 + lane];
        acc += v0 + v1;
    }
    if (j < dd) {
        const int s0 = __shfl(myn, j, 64);
        acc += y[(size_t)s0 * 128 + lane];
    }
    // rare tail: deg > 64
    for (int q = beg + 64; q < end; ++q) {
        const int s = nbr[q];
        acc += y[(size_t)s * 128 + lane];
    }

    const float dinv = 1.0f / fmaxf((float)deg, 1.0f);
    float v = acc * dinv + b1[lane] + y[(size_t)i * 128 + 64 + lane];

    // wave L2-norm (6 shuffles)
    float ss = v * v;
    #pragma unroll
    for (int m = 32; m >= 1; m >>= 1) ss += __shfl_xor(ss, m, 64);
    const float inv = 1.0f / fmaxf(sqrtf(ss), 1e-12f);
    const float hv = fmaxf(v * inv, 0.f);

    // gemm2 inline: lane f holds h[f]; W2l/W2r are [64][4]
    const float4 wl = *(const float4*)(W2l + lane * 4);
    const float4 wr = *(const float4*)(W2r + lane * 4);
    float p0 = hv * wl.x, p1 = hv * wl.y, p2 = hv * wl.z, p3 = hv * wl.w;
    float p4 = hv * wr.x, p5 = hv * wr.y, p6 = hv * wr.z, p7 = hv * wr.w;

    // multi-channel butterfly: 8 channels over 64 lanes in 10 shuffles.
    const bool b0 = (lane & 1) != 0;
    float s0_ = b0 ? p0 : p4;
    float s1_ = b0 ? p1 : p5;
    float s2_ = b0 ? p2 : p6;
    float s3_ = b0 ? p3 : p7;
    float q0 = (b0 ? p4 : p0) + __shfl_xor(s0_, 1, 64);
    float q1 = (b0 ? p5 : p1) + __shfl_xor(s1_, 1, 64);
    float q2 = (b0 ? p6 : p2) + __shfl_xor(s2_, 1, 64);
    float q3 = (b0 ? p7 : p3) + __shfl_xor(s3_, 1, 64);
    const bool b1b = (lane & 2) != 0;
    float t0 = b1b ? q0 : q2;
    float t1 = b1b ? q1 : q3;
    float r0 = (b1b ? q2 : q0) + __shfl_xor(t0, 2, 64);
    float r1 = (b1b ? q3 : q1) + __shfl_xor(t1, 2, 64);
    const bool b2 = (lane & 4) != 0;
    float u0 = b2 ? r0 : r1;
    float zv = (b2 ? r1 : r0) + __shfl_xor(u0, 4, 64);
    zv += __shfl_xor(zv, 8, 64);
    zv += __shfl_xor(zv, 16, 64);
    zv += __shfl_xor(zv, 32, 64);
    // lane -> channel: c = 4*b0 + 2*b1 + b2
    const int ch = 4 * (lane & 1) + ((lane & 2)) + ((lane >> 2) & 1);
    if (lane < 8) z[(size_t)i * 8 + ch] = zv;
}

// ===========================================================================
// fused2: per node (one thread): out = normalize(mean z_l[nbr] + b2 + z_r[i])
// ===========================================================================
__global__ void fused2_kernel(const float* __restrict__ z, const int* __restrict__ off,
                              const int* __restrict__ nbr, const float* __restrict__ b2,
                              float* __restrict__ out, int N)
{
    const int i = blockIdx.x * blockDim.x + threadIdx.x;
    if (i >= N) return;
    const int beg = off[i];
    const int end = off[i + 1];
    float4 acc = make_float4(0.f, 0.f, 0.f, 0.f);
    for (int j = beg; j < end; ++j) {
        const int s = nbr[j];
        const float4 t = *(const float4*)(z + (size_t)s * 8);
        acc.x += t.x; acc.y += t.y; acc.z += t.z; acc.w += t.w;
    }
    const float dinv = 1.0f / fmaxf((float)(end - beg), 1.0f);
    const float4 r  = *(const float4*)(z + (size_t)i * 8 + 4);
    const float4 bb = *(const float4*)(b2);
    float4 o;
    o.x = acc.x * dinv + bb.x + r.x;
    o.y = acc.y * dinv + bb.y + r.y;
    o.z = acc.z * dinv + bb.z + r.z;
    o.w = acc.w * dinv + bb.w + r.w;
    const float ss = o.x * o.x + o.y * o.y + o.z * o.z + o.w * o.w;
    const float inv = 1.0f / fmaxf(sqrtf(ss), 1e-12f);
    o.x *= inv; o.y *= inv; o.z *= inv; o.w *= inv;
    *(float4*)(out + (size_t)i * 4) = o;
}

// ===========================================================================
extern "C" void kernel_launch(void* const* d_in, const int* in_sizes, int n_in,
                              void* d_out, int out_size, void* d_ws, size_t ws_size,
                              hipStream_t stream)
{
    const float* x    = (const float*)d_in[0];
    const int*   ei   = (const int*)d_in[1];
    const float* W1l  = (const float*)d_in[2];
    const float* b1l  = (const float*)d_in[3];
    const float* W1r  = (const float*)d_in[4];
    const float* W2l  = (const float*)d_in[5];
    const float* b2l  = (const float*)d_in[6];
    const float* W2r  = (const float*)d_in[7];
    float* out = (float*)d_out;

    const int N = in_sizes[0] / DIN;
    const int E = in_sizes[1] / 2;
    const int* src = ei;
    const int* dst = ei + E;
    const int nblk = (N + 255) / 256;

    // workspace layout
    char* ws = (char*)d_ws;
    size_t woff = 0;
    auto alloc = [&](size_t bytes) {
        void* p = ws + woff;
        woff += (bytes + 255) & ~(size_t)255;
        return p;
    };
    float* y        = (float*)alloc((size_t)N * 128 * 4);
    float* z        = (float*)alloc((size_t)N * 8 * 4);
    short* WTh      = (short*)alloc((size_t)128 * 256 * 2);
    short* WTl      = (short*)alloc((size_t)128 * 256 * 2);
    int*   cnt      = (int*)alloc((size_t)2 * N * 4);    // cnt + cursor contiguous
    int*   cursor   = cnt + N;
    int*   off      = (int*)alloc((size_t)(N + 1) * 4);
    int*   nbr      = (int*)alloc((size_t)E * 4);
    int*   blocksum = (int*)alloc((size_t)nblk * 4);
    int*   blockoff = (int*)alloc((size_t)nblk * 4);

    hipMemsetAsync(cnt, 0, (size_t)2 * N * 4, stream);

    // --- CSR build
    count_kernel<<<(E + 255) / 256, 256, 0, stream>>>(dst, cnt, E);
    scan_a_kernel<<<nblk, 256, 0, stream>>>(cnt, blocksum, N);
    scan_b_kernel<<<1, 1024, 0, stream>>>(blocksum, blockoff, nblk);
    scan_c_kernel<<<nblk, 256, 0, stream>>>(cnt, blockoff, off, N);
    fill_kernel<<<(E + 255) / 256, 256, 0, stream>>>(src, dst, off, cursor, nbr, E);

    // --- layer 1 GEMM
    wprep_kernel<<<128, 256, 0, stream>>>(W1l, W1r, WTh, WTl);
    gemm1_mfma<<<(N + 63) / 64, 256, 0, stream>>>(x, WTh, WTl, y, N);

    // --- fused aggregate + norm + relu + gemm2
    fused1_kernel<<<(N + 3) / 4, 256, 0, stream>>>(y, off, nbr, b1l, W2l, W2r, z, N);

    // --- fused aggregate + norm (layer 2)
    fused2_kernel<<<(N + 255) / 256, 256, 0, stream>>>(z, off, nbr, b2l, out, N);
}